// Round 4
// baseline (7356.735 us; speedup 1.0000x reference)
//
#include <hip/hip_runtime.h>
#include <stdint.h>

// RNN LM: embed->shift -> 2-layer tanh RNN (T=2048) -> logits vs embedding^T
//         -> log_softmax -> gather at tokens -> sum (scalar out).
//
// k_rnn R5: partial-sum dataflow, no barriers, no LDS, no spill.
//  - Producers store per-wave raw column partials to P1/P2 with layout
//    [T+1][k][4] (transposed: one 16B quad = all 4 wave-partials of one k).
//    Stores are dword sc0 sc1; arrays poisoned to 0xFFFFFFFF (slot 0 = zeros).
//  - Consumers poll partial quads, reconstruct h = tanh_fast(aux + sum) in
//    registers (aux = xW1 row for h1, b2 for h2), then DPP-ring dot.
//  - L1: 32 WGs x 32 cols, 4 waves x 256 k (quad rings), 128 weights/lane.
//  - L2: 32 WGs x 16 cols, 4 waves x 384 k (three 16-lane PAIR rings),
//    96 weights/lane, 1 col/lane. All waves identical load -> no spill.
//  - k_conv reconstructs h2 from P2 (+b2, same tanh_fast) for logits path.

#define TSEQ 2048
#define NVOCAB 32000
#define DEMB 512
#define DHID 1024
#define CAN 0xFFFFFFFFu

typedef __attribute__((ext_vector_type(8))) short short8;
typedef __attribute__((ext_vector_type(4))) float f32x4;
typedef __attribute__((ext_vector_type(2))) float f32x2;
typedef unsigned long long u64;

__device__ __forceinline__ unsigned short f2bf(float f) {
  union { float f; unsigned u; } v; v.f = f;
  unsigned r = (v.u + 0x7FFFu + ((v.u >> 16) & 1u)) >> 16;
  return (unsigned short)r;
}

// 4 x 16B from one base (offsets 0,16,32,48), single waitcnt.
__device__ __forceinline__ void llc_ld16x4o(const float* p, f32x4& r0, f32x4& r1,
                                            f32x4& r2, f32x4& r3) {
  asm volatile(
      "global_load_dwordx4 %0, %4, off sc0 sc1\n\t"
      "global_load_dwordx4 %1, %4, off offset:16 sc0 sc1\n\t"
      "global_load_dwordx4 %2, %4, off offset:32 sc0 sc1\n\t"
      "global_load_dwordx4 %3, %4, off offset:48 sc0 sc1\n\t"
      "s_waitcnt vmcnt(0)"
      : "=&v"(r0), "=&v"(r1), "=&v"(r2), "=&v"(r3)
      : "v"(p) : "memory");
}

// 3 bases x 2 x 16B (offsets 0,16), single waitcnt.
__device__ __forceinline__ void llc_ld16x6(const float* pa, const float* pb,
                                           const float* pc, f32x4& a0, f32x4& a1,
                                           f32x4& b0, f32x4& b1, f32x4& c0,
                                           f32x4& c1) {
  asm volatile(
      "global_load_dwordx4 %0, %6, off sc0 sc1\n\t"
      "global_load_dwordx4 %1, %6, off offset:16 sc0 sc1\n\t"
      "global_load_dwordx4 %2, %7, off sc0 sc1\n\t"
      "global_load_dwordx4 %3, %7, off offset:16 sc0 sc1\n\t"
      "global_load_dwordx4 %4, %8, off sc0 sc1\n\t"
      "global_load_dwordx4 %5, %8, off offset:16 sc0 sc1\n\t"
      "s_waitcnt vmcnt(0)"
      : "=&v"(a0), "=&v"(a1), "=&v"(b0), "=&v"(b1), "=&v"(c0), "=&v"(c1)
      : "v"(pa), "v"(pb), "v"(pc) : "memory");
}

__device__ __forceinline__ void llc_st4(float* p, float v) {
  asm volatile("global_store_dword %0, %1, off sc0 sc1" :: "v"(p), "v"(v) : "memory");
}

__device__ __forceinline__ bool okq4(f32x4 v) {
  return (__float_as_uint(v.x) != CAN) & (__float_as_uint(v.y) != CAN) &
         (__float_as_uint(v.z) != CAN) & (__float_as_uint(v.w) != CAN);
}

// rotate right by 1 lane within each 16-lane row (row_ror:1 = 0x121)
__device__ __forceinline__ f32x4 rotq(f32x4 h) {
  f32x4 r;
  r.x = __int_as_float(__builtin_amdgcn_mov_dpp(__float_as_int(h.x), 0x121, 0xf, 0xf, false));
  r.y = __int_as_float(__builtin_amdgcn_mov_dpp(__float_as_int(h.y), 0x121, 0xf, 0xf, false));
  r.z = __int_as_float(__builtin_amdgcn_mov_dpp(__float_as_int(h.z), 0x121, 0xf, 0xf, false));
  r.w = __int_as_float(__builtin_amdgcn_mov_dpp(__float_as_int(h.w), 0x121, 0xf, 0xf, false));
  return r;
}
__device__ __forceinline__ f32x2 rotp(f32x2 h) {
  f32x2 r;
  r.x = __int_as_float(__builtin_amdgcn_mov_dpp(__float_as_int(h.x), 0x121, 0xf, 0xf, false));
  r.y = __int_as_float(__builtin_amdgcn_mov_dpp(__float_as_int(h.y), 0x121, 0xf, 0xf, false));
  return r;
}

__device__ __forceinline__ float tanh_fast(float x) {
  float ax = fabsf(x);
  float e = __expf(ax + ax);
  float t = 1.f - __fdividef(2.f, e + 1.f);
  return (x < 0.f) ? -t : t;
}

// ---------------- init: poison partial arrays; slot-0 rows = zeros ----------
__global__ void k_init(uint4* __restrict__ P1q, uint4* __restrict__ P2q) {
  const int n1 = (TSEQ + 1) * DHID;   // one quad per (s,k)
  const int n2 = (TSEQ + 1) * DEMB;
  uint4 can; can.x = CAN; can.y = CAN; can.z = CAN; can.w = CAN;
  uint4 zer; zer.x = 0u; zer.y = 0u; zer.z = 0u; zer.w = 0u;
  const int stride = gridDim.x * blockDim.x;
  for (int i = blockIdx.x * blockDim.x + threadIdx.x; i < n1 + n2; i += stride) {
    if (i < n1) P1q[i] = (i < DHID) ? zer : can;
    else {
      int j = i - n1;
      P2q[j] = (j < DEMB) ? zer : can;
    }
  }
}

// ---------------- xW1[t][j] = b1[j] + sum_e inputs[t][e]*W1[e][j] ------------
__global__ __launch_bounds__(256) void k_xw1(const int* __restrict__ tok,
                                             const float* __restrict__ emb,
                                             const float* __restrict__ W1,
                                             const float* __restrict__ b1,
                                             float* __restrict__ xW1) {
  __shared__ float in_lds[16 * DEMB];
  const int tid = threadIdx.x;
  const int rb = blockIdx.x >> 2, cb = blockIdx.x & 3;
  const int t0 = rb * 16, j0 = cb * 256;
  for (int idx = tid; idx < 16 * 128; idx += 256) {
    int r = idx >> 7, q = idx & 127;
    int t = t0 + r;
    float4 v;
    if (t == 0) { v.x = 0.f; v.y = 0.f; v.z = 0.f; v.w = 0.f; }
    else        { v = *(const float4*)(emb + (size_t)tok[t - 1] * DEMB + q * 4); }
    *(float4*)&in_lds[r * DEMB + q * 4] = v;
  }
  __syncthreads();
  const int j = j0 + tid;
  float acc[16];
  {
    float bb = b1[j];
#pragma unroll
    for (int r = 0; r < 16; ++r) acc[r] = bb;
  }
  for (int k = 0; k < DEMB; k += 4) {
    const float* wp = W1 + (size_t)k * DHID + j;
    float w0 = wp[0], w1 = wp[DHID], w2 = wp[2 * DHID], w3 = wp[3 * DHID];
#pragma unroll
    for (int r = 0; r < 16; ++r) {
      float4 h = *(const float4*)&in_lds[r * DEMB + k];
      acc[r] += h.x * w0;
      acc[r] += h.y * w1;
      acc[r] += h.z * w2;
      acc[r] += h.w * w3;
    }
  }
#pragma unroll
  for (int r = 0; r < 16; ++r) xW1[(size_t)(t0 + r) * DHID + j] = acc[r];
}

// ---------------- persistent RNN, partial-sum dataflow ----------------
// 64 WGs x 256 thr, no barriers, no LDS.
// WG 0..31: layer1 (32 cols). WG 32..63: layer2 (16 cols).
__global__ __launch_bounds__(256, 1) void k_rnn(const float* __restrict__ xW1,
                                                const float* __restrict__ U1,
                                                const float* __restrict__ W2,
                                                const float* __restrict__ U2,
                                                const float* __restrict__ b2,
                                                float* __restrict__ P1,
                                                float* __restrict__ P2) {
  const int tid = threadIdx.x;
  const int wg = blockIdx.x;
  const int l = tid & 63, w = tid >> 6;
  const int r = l >> 4, i = l & 15;

  if (wg < 32) {  // ---- layer 1 ----
    const int c0 = wg * 32;
    // wA[4j+e] = U1[256w+64r+4*((i-j)&15)+e][c0+i]; wB: col c0+i+16 (R4-proven)
    float wA[64], wB[64];
#pragma unroll
    for (int j = 0; j < 16; ++j) {
      int sl = (i - j) & 15;
      const float* up = U1 + (size_t)(256 * w + 64 * r + 4 * sl) * DHID + c0;
#pragma unroll
      for (int e = 0; e < 4; ++e) {
        wA[4 * j + e] = up[(size_t)e * DHID + i];
        wB[4 * j + e] = up[(size_t)e * DHID + i + 16];
      }
    }
    const float* pp = P1 + ((size_t)1 * DHID + 4 * tid) * 4;   // poll P1[st]
    const float* xp = xW1 + 4 * tid;                           // row st-1
    float* stp = P1 + ((size_t)2 * DHID + c0 + l) * 4 + w;     // store P1[st+1]
    // st=0: h1[0]=0 -> P1[1] partials are all zero
    if (l < 32) llc_st4(P1 + ((size_t)1 * DHID + c0 + l) * 4 + w, 0.f);
    for (int st = 1; st < TSEQ; ++st) {
      f32x4 xq = *(const f32x4*)xp;   // xW1[st-1], independent cached load
      f32x4 q0, q1, q2, q3;
      while (true) {
        llc_ld16x4o(pp, q0, q1, q2, q3);
        if (okq4(q0) & okq4(q1) & okq4(q2) & okq4(q3)) break;
      }
      f32x4 h;
      h.x = tanh_fast(xq.x + ((q0.x + q0.y) + (q0.z + q0.w)));
      h.y = tanh_fast(xq.y + ((q1.x + q1.y) + (q1.z + q1.w)));
      h.z = tanh_fast(xq.z + ((q2.x + q2.y) + (q2.z + q2.w)));
      h.w = tanh_fast(xq.w + ((q3.x + q3.y) + (q3.z + q3.w)));
      float a0 = 0.f, a1 = 0.f;
#pragma unroll
      for (int j = 0; j < 16; ++j) {
        a0 += h.x * wA[4 * j + 0]; a1 += h.x * wB[4 * j + 0];
        a0 += h.y * wA[4 * j + 1]; a1 += h.y * wB[4 * j + 1];
        a0 += h.z * wA[4 * j + 2]; a1 += h.z * wB[4 * j + 2];
        a0 += h.w * wA[4 * j + 3]; a1 += h.w * wB[4 * j + 3];
        if (j < 15) h = rotq(h);
      }
      a0 += __shfl_xor(a0, 16); a0 += __shfl_xor(a0, 32);
      a1 += __shfl_xor(a1, 16); a1 += __shfl_xor(a1, 32);
      if (l < 32) llc_st4(stp, (l < 16) ? a0 : a1);
      pp += (size_t)DHID * 4;
      xp += DHID;
      stp += (size_t)DHID * 4;
    }
  } else {  // ---- layer 2: 16 cols, 3 pair-rings/wave, 96 weights/lane ----
    const int c0 = (wg - 32) * 16;
    float wm0[32], wm1[32], wm2[32];
    f32x2 bia0, bia1, bia2;
    const float *ax0, *ax1, *ax2;
    const float *sp0, *sp1, *sp2;
    ptrdiff_t si0, si1, si2;
    bool z0, z1, z2;
#define L2SETUP(M, wmM, biaM, axM, spM, siM, zM)                                   \
    {                                                                              \
      int kb = 384 * w + 96 * r + 32 * M;                                          \
      _Pragma("unroll")                                                            \
      for (int j = 0; j < 16; ++j) {                                               \
        int kk = kb + 2 * ((i - j) & 15);                                          \
        const float* m0 = (kk < DHID) ? (W2 + (size_t)kk * DEMB)                   \
                                      : (U2 + (size_t)(kk - DHID) * DEMB);         \
        const float* m1 = (kk + 1 < DHID) ? (W2 + (size_t)(kk + 1) * DEMB)         \
                                          : (U2 + (size_t)(kk + 1 - DHID) * DEMB); \
        wmM[2 * j] = m0[c0 + i];                                                   \
        wmM[2 * j + 1] = m1[c0 + i];                                               \
      }                                                                            \
      int kr = kb + 2 * i;                                                         \
      zM = (kr >= DHID);                                                           \
      int bi = zM ? (kr - DHID) : 0;                                               \
      biaM.x = b2[bi]; biaM.y = b2[bi + 1];                                        \
      axM = xW1 + (zM ? (kr & (DHID - 1)) : kr);                                   \
      spM = zM ? (P2 + ((size_t)(kr - DHID)) * 4)                                  \
               : (P1 + ((size_t)1 * DHID + kr) * 4);                               \
      siM = zM ? (ptrdiff_t)(DEMB * 4) : (ptrdiff_t)(DHID * 4);                    \
    }
    L2SETUP(0, wm0, bia0, ax0, sp0, si0, z0)
    L2SETUP(1, wm1, bia1, ax1, sp1, si1, z1)
    L2SETUP(2, wm2, bia2, ax2, sp2, si2, z2)
#undef L2SETUP
    float* stp = P2 + ((size_t)1 * DEMB + c0 + (l & 15)) * 4 + w;
    for (int t = 0; t < TSEQ; ++t) {
      f32x2 x0 = *(const f32x2*)ax0;
      f32x2 x1 = *(const f32x2*)ax1;
      f32x2 x2 = *(const f32x2*)ax2;
      f32x4 A0, A1, B0, B1, C0, C1;
      while (true) {
        llc_ld16x6(sp0, sp1, sp2, A0, A1, B0, B1, C0, C1);
        if (okq4(A0) & okq4(A1) & okq4(B0) & okq4(B1) & okq4(C0) & okq4(C1)) break;
      }
      f32x2 v0 = z0 ? bia0 : x0;
      f32x2 v1 = z1 ? bia1 : x1;
      f32x2 v2 = z2 ? bia2 : x2;
      const bool zz = (t == 0);
      f32x2 hA, hB, hC;
      hA.x = (zz & z0) ? 0.f : tanh_fast(v0.x + ((A0.x + A0.y) + (A0.z + A0.w)));
      hA.y = (zz & z0) ? 0.f : tanh_fast(v0.y + ((A1.x + A1.y) + (A1.z + A1.w)));
      hB.x = (zz & z1) ? 0.f : tanh_fast(v1.x + ((B0.x + B0.y) + (B0.z + B0.w)));
      hB.y = (zz & z1) ? 0.f : tanh_fast(v1.y + ((B1.x + B1.y) + (B1.z + B1.w)));
      hC.x = (zz & z2) ? 0.f : tanh_fast(v2.x + ((C0.x + C0.y) + (C0.z + C0.w)));
      hC.y = (zz & z2) ? 0.f : tanh_fast(v2.y + ((C1.x + C1.y) + (C1.z + C1.w)));
      float a0 = 0.f, a1 = 0.f, a2 = 0.f;
#pragma unroll
      for (int j = 0; j < 16; ++j) {
        a0 += hA.x * wm0[2 * j]; a0 += hA.y * wm0[2 * j + 1];
        a1 += hB.x * wm1[2 * j]; a1 += hB.y * wm1[2 * j + 1];
        a2 += hC.x * wm2[2 * j]; a2 += hC.y * wm2[2 * j + 1];
        if (j < 15) { hA = rotp(hA); hB = rotp(hB); hC = rotp(hC); }
      }
      float a = (a0 + a1) + a2;
      a += __shfl_xor(a, 16); a += __shfl_xor(a, 32);
      if (l < 16) llc_st4(stp, a);
      sp0 += si0; sp1 += si1; sp2 += si2;
      ax0 += DHID; ax1 += DHID; ax2 += DHID;
      stp += (size_t)DEMB * 4;
    }
  }
}

// ------- casts + h2 reconstruction: embB, h2b (bf16), h2buf (f32) -----------
__global__ void k_conv(const float* __restrict__ emb, const float* __restrict__ P2,
                       const float* __restrict__ b2,
                       unsigned short* __restrict__ embB,
                       unsigned short* __restrict__ h2b, float* __restrict__ h2buf) {
  const int n1 = NVOCAB * DEMB / 4;
  const int n2 = TSEQ * DEMB / 4;
  const int stride = gridDim.x * blockDim.x;
  for (int idx = blockIdx.x * blockDim.x + threadIdx.x; idx < n1 + n2; idx += stride) {
    if (idx < n1) {
      float4 v = ((const float4*)emb)[idx];
      ushort4 o;
      o.x = f2bf(v.x); o.y = f2bf(v.y); o.z = f2bf(v.z); o.w = f2bf(v.w);
      ((ushort4*)embB)[idx] = o;
    } else {
      int j = idx - n1;
      int s = 1 + (j >> 7);           // DEMB/4 = 128 quads per row
      int q = (j & 127) << 2;
      const float* pb = P2 + ((size_t)s * DEMB + q) * 4;
      float4 A = *(const float4*)pb;
      float4 B = *(const float4*)(pb + 4);
      float4 C = *(const float4*)(pb + 8);
      float4 D = *(const float4*)(pb + 12);
      float4 bq = *(const float4*)(b2 + q);
      float4 h;
      h.x = tanh_fast(bq.x + ((A.x + A.y) + (A.z + A.w)));
      h.y = tanh_fast(bq.y + ((B.x + B.y) + (B.z + B.w)));
      h.z = tanh_fast(bq.z + ((C.x + C.y) + (C.z + C.w)));
      h.w = tanh_fast(bq.w + ((D.x + D.y) + (D.z + D.w)));
      *(float4*)(h2buf + (size_t)s * DEMB + q) = h;
      ushort4 o;
      o.x = f2bf(h.x); o.y = f2bf(h.y); o.z = f2bf(h.z); o.w = f2bf(h.w);
      ((ushort4*)h2b)[((size_t)(s - 1) * DEMB + q) >> 2] = o;
    }
  }
}

// ---------------- fused logits GEMM + online softmax stats ----------------
__global__ __launch_bounds__(256, 1) void k_logits(const unsigned short* __restrict__ Ab,
                                                   const unsigned short* __restrict__ Bb,
                                                   float* __restrict__ pmax,
                                                   float* __restrict__ psum) {
  extern __shared__ char smem_dyn[];
  unsigned short* As = (unsigned short*)smem_dyn;       // 128*512*2 = 131072 B
  float* sstat = (float*)(smem_dyn + 131072);           // 4*128*2 f32
  const int tid = threadIdx.x;
  const int rb = blockIdx.x >> 4, ch = blockIdx.x & 15;
  const int r0 = rb * 128, v0 = ch * 2000;
  for (int idx = tid; idx < 128 * 64; idx += 256) {
    int row = idx >> 6, kq = idx & 63;
    uint4 v = *(const uint4*)(Ab + (size_t)(r0 + row) * DEMB + kq * 8);
    int byte = (row * 1024 + kq * 16) ^ ((row & 7) << 4);
    *(uint4*)((char*)As + byte) = v;
  }
  __syncthreads();
  const int wv = tid >> 6, lane = tid & 63;
  const int col = lane & 15, kg = lane >> 4;
  f32x4 rmax[8], rsum[8];
#pragma unroll
  for (int t = 0; t < 8; ++t) { rmax[t] = (f32x4)(-3.0e38f); rsum[t] = (f32x4)(0.f); }

  for (int strip = wv; strip < 125; strip += 4) {
    const unsigned short* bp = Bb + (size_t)(v0 + strip * 16 + col) * DEMB + kg * 8;
    f32x4 acc[8];
#pragma unroll
    for (int t = 0; t < 8; ++t) acc[t] = (f32x4)(0.f);
#pragma unroll
    for (int ks = 0; ks < 16; ++ks) {
      short8 bfrag = *(const short8*)(bp + ks * 32);
#pragma unroll
      for (int t = 0; t < 8; ++t) {
        int row = t * 16 + col;
        int byte = (row * 1024 + ks * 64 + kg * 16) ^ ((row & 7) << 4);
        short8 afrag = *(const short8*)((const char*)As + byte);
        acc[t] = __builtin_amdgcn_mfma_f32_16x16x32_bf16(afrag, bfrag, acc[t], 0, 0, 0);
      }
    }
#pragma unroll
    for (int t = 0; t < 8; ++t) {
      f32x4 v = acc[t];
      f32x4 mx = v;
#pragma unroll
      for (int d = 1; d < 16; d <<= 1) {
        mx.x = fmaxf(mx.x, __shfl_xor(mx.x, d));
        mx.y = fmaxf(mx.y, __shfl_xor(mx.y, d));
        mx.z = fmaxf(mx.z, __shfl_xor(mx.z, d));
        mx.w = fmaxf(mx.w, __shfl_xor(mx.w, d));
      }
      f32x4 nm;
      nm.x = fmaxf(rmax[t].x, mx.x);
      nm.y = fmaxf(rmax[t].y, mx.y);
      nm.z = fmaxf(rmax[t].z, mx.z);
      nm.w = fmaxf(rmax[t].w, mx.w);
      f32x4 e;
      e.x = __expf(v.x - nm.x); e.y = __expf(v.y - nm.y);
      e.z = __expf(v.z - nm.z); e.w = __expf(v.w - nm.w);
#pragma unroll
      for (int d = 1; d < 16; d <<= 1) {
        e.x += __shfl_xor(e.x, d);
        e.y += __shfl_xor(e.y, d);
        e.z += __shfl_xor(e.z, d);
        e.w += __shfl_xor(e.w, d);
      }
      rsum[t].x = rsum[t].x * __expf(rmax[t].x - nm.x) + e.x;
      rsum[t].y = rsum[t].y * __expf(rmax[t].y - nm.y) + e.y;
      rsum[t].z = rsum[t].z * __expf(rmax[t].z - nm.z) + e.z;
      rsum[t].w = rsum[t].w * __expf(rmax[t].w - nm.w) + e.w;
      rmax[t] = nm;
    }
  }
  if (col == 0) {
#pragma unroll
    for (int t = 0; t < 8; ++t) {
#pragma unroll
      for (int r = 0; r < 4; ++r) {
        int row = t * 16 + kg * 4 + r;
        sstat[(wv * 128 + row) * 2 + 0] = rmax[t][r];
        sstat[(wv * 128 + row) * 2 + 1] = rsum[t][r];
      }
    }
  }
  __syncthreads();
  if (tid < 128) {
    float m = -3.0e38f, ssum = 0.f;
#pragma unroll
    for (int w2 = 0; w2 < 4; ++w2) {
      float pm = sstat[(w2 * 128 + tid) * 2 + 0];
      float ps = sstat[(w2 * 128 + tid) * 2 + 1];
      float nm2 = fmaxf(m, pm);
      ssum = ssum * __expf(m - nm2) + ps * __expf(pm - nm2);
      m = nm2;
    }
    pmax[(size_t)(r0 + tid) * 16 + ch] = m;
    psum[(size_t)(r0 + tid) * 16 + ch] = ssum;
  }
}

// ---------------- target logit in f32: dot(h2[t], emb[tok[t]]) ----------------
__global__ __launch_bounds__(256) void k_tlogit(const int* __restrict__ tok,
                                                const float* __restrict__ emb,
                                                const float* __restrict__ h2buf,
                                                float* __restrict__ tlog) {
  const int wv = threadIdx.x >> 6, lane = threadIdx.x & 63;
  const int wgid = blockIdx.x * 4 + wv;
  for (int t = wgid; t < TSEQ; t += 128) {
    const float* hp = h2buf + (size_t)(t + 1) * DEMB + lane * 8;
    const float* ep = emb + (size_t)tok[t] * DEMB + lane * 8;
    float4 h0 = *(const float4*)hp, h1v = *(const float4*)(hp + 4);
    float4 e0 = *(const float4*)ep, e1v = *(const float4*)(ep + 4);
    float d = h0.x * e0.x + h0.y * e0.y + h0.z * e0.z + h0.w * e0.w +
              h1v.x * e1v.x + h1v.y * e1v.y + h1v.z * e1v.z + h1v.w * e1v.w;
    for (int m = 1; m < 64; m <<= 1) d += __shfl_xor(d, m);
    if (lane == 0) tlog[t] = d;
  }
}

// ---------------- final: sum_t (tlogit - lse) ----------------
__global__ void k_final(const float* __restrict__ pmax, const float* __restrict__ psum,
                        const float* __restrict__ tlog, float* __restrict__ out) {
  __shared__ float red[4];
  float local = 0.f;
  for (int t = threadIdx.x; t < TSEQ; t += 256) {
    float m = -3.0e38f, s = 0.f;
#pragma unroll
    for (int c = 0; c < 16; ++c) {
      float pm = pmax[t * 16 + c], ps = psum[t * 16 + c];
      float nm = fmaxf(m, pm);
      s = s * __expf(m - nm) + ps * __expf(pm - nm);
      m = nm;
    }
    local += tlog[t] - (m + __logf(s));
  }
  for (int d = 1; d < 64; d <<= 1) local += __shfl_xor(local, d);
  if ((threadIdx.x & 63) == 0) red[threadIdx.x >> 6] = local;
  __syncthreads();
  if (threadIdx.x == 0) out[0] = red[0] + red[1] + red[2] + red[3];
}

// ---------------- host ----------------
extern "C" void kernel_launch(void* const* d_in, const int* in_sizes, int n_in,
                              void* d_out, int out_size, void* d_ws, size_t ws_size,
                              hipStream_t stream) {
  (void)in_sizes; (void)n_in; (void)out_size; (void)ws_size;
  const int*   tok = (const int*)d_in[0];
  const float* emb = (const float*)d_in[1];
  const float* W1  = (const float*)d_in[2];
  const float* U1  = (const float*)d_in[3];
  const float* b1  = (const float*)d_in[4];
  const float* W2  = (const float*)d_in[5];
  const float* U2  = (const float*)d_in[6];
  const float* b2  = (const float*)d_in[7];
  float* out = (float*)d_out;

  char* ws = (char*)d_ws;
  size_t off = 0;
  auto alloc = [&](size_t bytes) {
    char* p = ws + off;
    off = (off + bytes + 255) & ~(size_t)255;
    return p;
  };
  float* h2buf = (float*)alloc((size_t)(TSEQ + 1) * DEMB * 4);
  unsigned short* h2b = (unsigned short*)alloc((size_t)TSEQ * DEMB * 2);
  float* pmax = (float*)alloc((size_t)TSEQ * 16 * 4);
  float* psum = (float*)alloc((size_t)TSEQ * 16 * 4);
  float* tlog = (float*)alloc((size_t)TSEQ * 4);
  // big region during k_rnn: [P1 33.6MB][xW1 8.4MB][P2 16.8MB].
  // embB (32.77MB) overlays from offset 0 afterwards -> clobbers P1 only
  // (dead after k_rnn); xW1 (offset 33.57MB) and P2 (offset 41.96MB) are
  // beyond embB's end; k_conv reads P2 safely.
  size_t sz_P1 = (size_t)(TSEQ + 1) * DHID * 4 * 4;  // 33,570,816
  size_t sz_xw1 = (size_t)TSEQ * DHID * 4;           //  8,388,608
  size_t sz_P2 = (size_t)(TSEQ + 1) * DEMB * 4 * 4;  // 16,785,408
  size_t sz_embB = (size_t)NVOCAB * DEMB * 2;        // 32,768,000
  size_t big_sz = sz_P1 + sz_xw1 + sz_P2;
  if (sz_embB > big_sz) big_sz = sz_embB;
  char* big = alloc(big_sz);
  float* P1 = (float*)big;
  float* xW1 = (float*)(big + sz_P1);
  float* P2 = (float*)(big + sz_P1 + sz_xw1);
  unsigned short* embB = (unsigned short*)big;

  k_init<<<dim3(512), dim3(256), 0, stream>>>((uint4*)P1, (uint4*)P2);
  k_xw1<<<dim3(512), dim3(256), 0, stream>>>(tok, emb, W1, b1, xW1);
  k_rnn<<<dim3(64), dim3(256), 0, stream>>>(xW1, U1, W2, U2, b2, P1, P2);
  k_conv<<<dim3(2048), dim3(256), 0, stream>>>(emb, P2, b2, embB, h2b, h2buf);
  k_logits<<<dim3(256), dim3(256), 135168, stream>>>(h2b, embB, pmax, psum);
  k_tlogit<<<dim3(32), dim3(256), 0, stream>>>(tok, emb, h2buf, tlog);
  k_final<<<dim3(1), dim3(256), 0, stream>>>(pmax, psum, tlog, out);
}

// Round 5
// 3810.116 us; speedup vs baseline: 1.9308x; 1.9308x over previous
//
#include <hip/hip_runtime.h>
#include <stdint.h>

// RNN LM: embed->shift -> 2-layer tanh RNN (T=2048) -> logits vs embedding^T
//         -> log_softmax -> gather at tokens -> sum (scalar out).
//
// k_rnn R6: finished-h canary dataflow (R4) + balanced wave geometry (R5's
// split), no heavy waves, slim finalize.
//  - h1v/h2v: [T+1][D] f32, poisoned 0xFFFFFFFF (row 0 = zeros) by k_init.
//  - Producers: finalist lanes (tid<16) store ONE dword per col, sc0 sc1.
//  - Consumers: poll own quad/pair via dwordx4/dwordx2 sc0 sc1; per-dword
//    canary checks tolerate partial arrival.
//  - L1: 64 WGs x 16 cols; wave w, row r: quad-ring over 64 k of U1;
//    64 weights/lane.
//  - L2: 32 WGs x 16 cols; wave w, row r: quad-ring over 64 h1-k (W2) +
//    pair-ring over 32 h2-k (U2); 96 weights/lane; all waves symmetric.
//  - Combine: xor16+xor32 in-wave, LDS cmb[2][16*8] cross-wave, 1 barrier,
//    tid<16 finalize (b128 read, sum4, tanh_fast, dword store).

#define TSEQ 2048
#define NVOCAB 32000
#define DEMB 512
#define DHID 1024
#define CAN 0xFFFFFFFFu

typedef __attribute__((ext_vector_type(8))) short short8;
typedef __attribute__((ext_vector_type(4))) float f32x4;
typedef __attribute__((ext_vector_type(2))) float f32x2;
typedef unsigned long long u64;

__device__ __forceinline__ unsigned short f2bf(float f) {
  union { float f; unsigned u; } v; v.f = f;
  unsigned r = (v.u + 0x7FFFu + ((v.u >> 16) & 1u)) >> 16;
  return (unsigned short)r;
}

__device__ __forceinline__ f32x4 llc_ld16(const float* p) {
  f32x4 r;
  asm volatile("global_load_dwordx4 %0, %1, off sc0 sc1\n\ts_waitcnt vmcnt(0)"
               : "=&v"(r) : "v"(p) : "memory");
  return r;
}

// dwordx4 + dwordx2 from two bases, single waitcnt.
__device__ __forceinline__ void llc_ld16_8(const float* pa, const float* pb,
                                           f32x4& a, f32x2& b) {
  asm volatile("global_load_dwordx4 %0, %2, off sc0 sc1\n\t"
               "global_load_dwordx2 %1, %3, off sc0 sc1\n\t"
               "s_waitcnt vmcnt(0)"
               : "=&v"(a), "=&v"(b) : "v"(pa), "v"(pb) : "memory");
}

__device__ __forceinline__ void llc_st4(float* p, float v) {
  asm volatile("global_store_dword %0, %1, off sc0 sc1" :: "v"(p), "v"(v) : "memory");
}

__device__ __forceinline__ bool okq4(f32x4 v) {
  return (__float_as_uint(v.x) != CAN) & (__float_as_uint(v.y) != CAN) &
         (__float_as_uint(v.z) != CAN) & (__float_as_uint(v.w) != CAN);
}
__device__ __forceinline__ bool okp2(f32x2 v) {
  return (__float_as_uint(v.x) != CAN) & (__float_as_uint(v.y) != CAN);
}

// rotate right by 1 lane within each 16-lane row (row_ror:1 = 0x121)
__device__ __forceinline__ f32x4 rotq(f32x4 h) {
  f32x4 r;
  r.x = __int_as_float(__builtin_amdgcn_mov_dpp(__float_as_int(h.x), 0x121, 0xf, 0xf, false));
  r.y = __int_as_float(__builtin_amdgcn_mov_dpp(__float_as_int(h.y), 0x121, 0xf, 0xf, false));
  r.z = __int_as_float(__builtin_amdgcn_mov_dpp(__float_as_int(h.z), 0x121, 0xf, 0xf, false));
  r.w = __int_as_float(__builtin_amdgcn_mov_dpp(__float_as_int(h.w), 0x121, 0xf, 0xf, false));
  return r;
}
__device__ __forceinline__ f32x2 rotp(f32x2 h) {
  f32x2 r;
  r.x = __int_as_float(__builtin_amdgcn_mov_dpp(__float_as_int(h.x), 0x121, 0xf, 0xf, false));
  r.y = __int_as_float(__builtin_amdgcn_mov_dpp(__float_as_int(h.y), 0x121, 0xf, 0xf, false));
  return r;
}

__device__ __forceinline__ float tanh_fast(float x) {
  float ax = fabsf(x);
  float e = __expf(ax + ax);
  float t = 1.f - __fdividef(2.f, e + 1.f);
  return (x < 0.f) ? -t : t;
}

// ---------------- init: poison all slots; row 0 = real zeros ----------------
__global__ void k_init(uint4* __restrict__ h1v4, uint4* __restrict__ h2v4) {
  const int n1 = (TSEQ + 1) * DHID / 4;
  const int n2 = (TSEQ + 1) * DEMB / 4;
  uint4 can; can.x = CAN; can.y = CAN; can.z = CAN; can.w = CAN;
  uint4 zer; zer.x = 0u; zer.y = 0u; zer.z = 0u; zer.w = 0u;
  const int stride = gridDim.x * blockDim.x;
  for (int i = blockIdx.x * blockDim.x + threadIdx.x; i < n1 + n2; i += stride) {
    if (i < n1) {
      h1v4[i] = (i < DHID / 4) ? zer : can;
    } else {
      int j = i - n1;
      h2v4[j] = (j < DEMB / 4) ? zer : can;
    }
  }
}

// ---------------- xW1[t][j] = b1[j] + sum_e inputs[t][e]*W1[e][j] ------------
__global__ __launch_bounds__(256) void k_xw1(const int* __restrict__ tok,
                                             const float* __restrict__ emb,
                                             const float* __restrict__ W1,
                                             const float* __restrict__ b1,
                                             float* __restrict__ xW1) {
  __shared__ float in_lds[16 * DEMB];
  const int tid = threadIdx.x;
  const int rb = blockIdx.x >> 2, cb = blockIdx.x & 3;
  const int t0 = rb * 16, j0 = cb * 256;
  for (int idx = tid; idx < 16 * 128; idx += 256) {
    int r = idx >> 7, q = idx & 127;
    int t = t0 + r;
    float4 v;
    if (t == 0) { v.x = 0.f; v.y = 0.f; v.z = 0.f; v.w = 0.f; }
    else        { v = *(const float4*)(emb + (size_t)tok[t - 1] * DEMB + q * 4); }
    *(float4*)&in_lds[r * DEMB + q * 4] = v;
  }
  __syncthreads();
  const int j = j0 + tid;
  float acc[16];
  {
    float bb = b1[j];
#pragma unroll
    for (int r = 0; r < 16; ++r) acc[r] = bb;
  }
  for (int k = 0; k < DEMB; k += 4) {
    const float* wp = W1 + (size_t)k * DHID + j;
    float w0 = wp[0], w1 = wp[DHID], w2 = wp[2 * DHID], w3 = wp[3 * DHID];
#pragma unroll
    for (int r = 0; r < 16; ++r) {
      float4 h = *(const float4*)&in_lds[r * DEMB + k];
      acc[r] += h.x * w0;
      acc[r] += h.y * w1;
      acc[r] += h.z * w2;
      acc[r] += h.w * w3;
    }
  }
#pragma unroll
  for (int r = 0; r < 16; ++r) xW1[(size_t)(t0 + r) * DHID + j] = acc[r];
}

// ---------------- persistent RNN ----------------
// 96 WGs x 256 thr. WG 0..63: layer1 (16 cols). WG 64..95: layer2 (16 cols).
__global__ __launch_bounds__(256, 1) void k_rnn(const float* __restrict__ xW1,
                                                const float* __restrict__ U1,
                                                const float* __restrict__ W2,
                                                const float* __restrict__ U2,
                                                const float* __restrict__ b2,
                                                float* __restrict__ h1v,
                                                float* __restrict__ h2v,
                                                float* __restrict__ h2buf) {
  __shared__ float cmb[2][128];   // [parity][col*8 + wave]
  const int tid = threadIdx.x;
  const int wg = blockIdx.x;
  const int l = tid & 63, w = tid >> 6;
  const int r = l >> 4, i = l & 15;

  if (wg < 64) {  // ---- layer 1: h1[t] = tanh(xW1[t] + h1[t-1]@U1) ----
    const int c0 = wg * 16;
    // wA[4j+e] = U1[256w + 64r + 4*((i-j)&15) + e][c0+i]
    float wA[64];
#pragma unroll
    for (int j = 0; j < 16; ++j) {
      int sl = (i - j) & 15;
      const float* up = U1 + (size_t)(256 * w + 64 * r + 4 * sl) * DHID + c0 + i;
#pragma unroll
      for (int e = 0; e < 4; ++e) wA[4 * j + e] = up[(size_t)e * DHID];
    }
    const float* pp = h1v + 4 * tid;              // poll row st (st=0 -> zeros)
    const float* xp = xW1 + c0 + (tid & 15);      // finalists (tid<16)
    float* stp = h1v + DHID + c0 + tid;           // store row st+1 (tid<16)
    for (int st = 0; st < TSEQ; ++st) {
      float xv = *xp;                             // early, independent
      f32x4 h;
      while (true) { h = llc_ld16(pp); if (okq4(h)) break; }
      f32x4 ac = (f32x4)(0.f);
#pragma unroll
      for (int j = 0; j < 16; ++j) {
        ac.x += h.x * wA[4 * j + 0];
        ac.y += h.y * wA[4 * j + 1];
        ac.z += h.z * wA[4 * j + 2];
        ac.w += h.w * wA[4 * j + 3];
        if (j < 15) h = rotq(h);
      }
      float a = (ac.x + ac.y) + (ac.z + ac.w);
      a += __shfl_xor(a, 16);
      a += __shfl_xor(a, 32);
      const int par = st & 1;
      if (l < 16) cmb[par][i * 8 + w] = a;
      __syncthreads();
      if (tid < 16) {
        f32x4 c4 = *(const f32x4*)&cmb[par][tid * 8];
        float hv = tanh_fast(xv + ((c4.x + c4.y) + (c4.z + c4.w)));
        llc_st4(stp, hv);
      }
      pp += DHID; xp += DHID; stp += DHID;
    }
  } else {  // ---- layer 2: h2[t] = tanh(h1[t]@W2 + h2[t-1]@U2 + b2) ----
    const int c0 = (wg - 64) * 16;
    // quad-ring (W2, 64 k of h1) + pair-ring (U2, 32 k of h2prev)
    float wq[64], wp[32];
#pragma unroll
    for (int j = 0; j < 16; ++j) {
      int sl = (i - j) & 15;
      const float* m = W2 + (size_t)(256 * w + 64 * r + 4 * sl) * DEMB + c0 + i;
#pragma unroll
      for (int e = 0; e < 4; ++e) wq[4 * j + e] = m[(size_t)e * DEMB];
      const float* u = U2 + (size_t)(128 * w + 32 * r + 2 * sl) * DEMB + c0 + i;
      wp[2 * j + 0] = u[0];
      wp[2 * j + 1] = u[DEMB];
    }
    const float bias = b2[c0 + (tid & 15)];
    const float* ppA = h1v + DHID + 256 * w + 64 * r + 4 * i;  // h1[t] = row t+1
    const float* ppB = h2v + 128 * w + 32 * r + 2 * i;         // h2[t-1] = row t
    float* stp = h2v + DEMB + c0 + tid;                        // row t+1 (tid<16)
    float* hb = h2buf + DEMB + c0 + tid;
    for (int t = 0; t < TSEQ; ++t) {
      f32x4 hq; f32x2 hp;
      while (true) {
        llc_ld16_8(ppA, ppB, hq, hp);
        if (okq4(hq) & okp2(hp)) break;
      }
      f32x4 aq = (f32x4)(0.f);
      f32x2 ap = (f32x2)(0.f);
#pragma unroll
      for (int j = 0; j < 16; ++j) {
        aq.x += hq.x * wq[4 * j + 0];
        aq.y += hq.y * wq[4 * j + 1];
        aq.z += hq.z * wq[4 * j + 2];
        aq.w += hq.w * wq[4 * j + 3];
        ap.x += hp.x * wp[2 * j + 0];
        ap.y += hp.y * wp[2 * j + 1];
        if (j < 15) { hq = rotq(hq); hp = rotp(hp); }
      }
      float a = ((aq.x + aq.y) + (aq.z + aq.w)) + (ap.x + ap.y);
      a += __shfl_xor(a, 16);
      a += __shfl_xor(a, 32);
      const int par = t & 1;
      if (l < 16) cmb[par][i * 8 + w] = a;
      __syncthreads();
      if (tid < 16) {
        f32x4 c4 = *(const f32x4*)&cmb[par][tid * 8];
        float hv = tanh_fast(bias + ((c4.x + c4.y) + (c4.z + c4.w)));
        llc_st4(stp, hv);
        *hb = hv;
      }
      ppA += DHID; ppB += DEMB; stp += DEMB; hb += DEMB;
    }
  }
}

// ---------------- f32 -> bf16 casts (embedding + h2 history) ----------------
__global__ void k_conv(const float* __restrict__ emb, const float* __restrict__ h2f,
                       unsigned short* __restrict__ embB, unsigned short* __restrict__ h2b) {
  const int n1 = NVOCAB * DEMB / 4;
  const int n2 = TSEQ * DEMB / 4;
  const int stride = gridDim.x * blockDim.x;
  for (int i = blockIdx.x * blockDim.x + threadIdx.x; i < n1 + n2; i += stride) {
    float4 v;
    if (i < n1) v = ((const float4*)emb)[i];
    else        v = ((const float4*)h2f)[i - n1];
    ushort4 o;
    o.x = f2bf(v.x); o.y = f2bf(v.y); o.z = f2bf(v.z); o.w = f2bf(v.w);
    if (i < n1) ((ushort4*)embB)[i] = o;
    else        ((ushort4*)h2b)[i - n1] = o;
  }
}

// ---------------- fused logits GEMM + online softmax stats ----------------
__global__ __launch_bounds__(256, 1) void k_logits(const unsigned short* __restrict__ Ab,
                                                   const unsigned short* __restrict__ Bb,
                                                   float* __restrict__ pmax,
                                                   float* __restrict__ psum) {
  extern __shared__ char smem_dyn[];
  unsigned short* As = (unsigned short*)smem_dyn;       // 128*512*2 = 131072 B
  float* sstat = (float*)(smem_dyn + 131072);           // 4*128*2 f32
  const int tid = threadIdx.x;
  const int rb = blockIdx.x >> 4, ch = blockIdx.x & 15;
  const int r0 = rb * 128, v0 = ch * 2000;
  for (int idx = tid; idx < 128 * 64; idx += 256) {
    int row = idx >> 6, kq = idx & 63;
    uint4 v = *(const uint4*)(Ab + (size_t)(r0 + row) * DEMB + kq * 8);
    int byte = (row * 1024 + kq * 16) ^ ((row & 7) << 4);
    *(uint4*)((char*)As + byte) = v;
  }
  __syncthreads();
  const int wv = tid >> 6, lane = tid & 63;
  const int col = lane & 15, kg = lane >> 4;
  f32x4 rmax[8], rsum[8];
#pragma unroll
  for (int t = 0; t < 8; ++t) { rmax[t] = (f32x4)(-3.0e38f); rsum[t] = (f32x4)(0.f); }

  for (int strip = wv; strip < 125; strip += 4) {
    const unsigned short* bp = Bb + (size_t)(v0 + strip * 16 + col) * DEMB + kg * 8;
    f32x4 acc[8];
#pragma unroll
    for (int t = 0; t < 8; ++t) acc[t] = (f32x4)(0.f);
#pragma unroll
    for (int ks = 0; ks < 16; ++ks) {
      short8 bfrag = *(const short8*)(bp + ks * 32);
#pragma unroll
      for (int t = 0; t < 8; ++t) {
        int row = t * 16 + col;
        int byte = (row * 1024 + ks * 64 + kg * 16) ^ ((row & 7) << 4);
        short8 afrag = *(const short8*)((const char*)As + byte);
        acc[t] = __builtin_amdgcn_mfma_f32_16x16x32_bf16(afrag, bfrag, acc[t], 0, 0, 0);
      }
    }
#pragma unroll
    for (int t = 0; t < 8; ++t) {
      f32x4 v = acc[t];
      f32x4 mx = v;
#pragma unroll
      for (int d = 1; d < 16; d <<= 1) {
        mx.x = fmaxf(mx.x, __shfl_xor(mx.x, d));
        mx.y = fmaxf(mx.y, __shfl_xor(mx.y, d));
        mx.z = fmaxf(mx.z, __shfl_xor(mx.z, d));
        mx.w = fmaxf(mx.w, __shfl_xor(mx.w, d));
      }
      f32x4 nm;
      nm.x = fmaxf(rmax[t].x, mx.x);
      nm.y = fmaxf(rmax[t].y, mx.y);
      nm.z = fmaxf(rmax[t].z, mx.z);
      nm.w = fmaxf(rmax[t].w, mx.w);
      f32x4 e;
      e.x = __expf(v.x - nm.x); e.y = __expf(v.y - nm.y);
      e.z = __expf(v.z - nm.z); e.w = __expf(v.w - nm.w);
#pragma unroll
      for (int d = 1; d < 16; d <<= 1) {
        e.x += __shfl_xor(e.x, d);
        e.y += __shfl_xor(e.y, d);
        e.z += __shfl_xor(e.z, d);
        e.w += __shfl_xor(e.w, d);
      }
      rsum[t].x = rsum[t].x * __expf(rmax[t].x - nm.x) + e.x;
      rsum[t].y = rsum[t].y * __expf(rmax[t].y - nm.y) + e.y;
      rsum[t].z = rsum[t].z * __expf(rmax[t].z - nm.z) + e.z;
      rsum[t].w = rsum[t].w * __expf(rmax[t].w - nm.w) + e.w;
      rmax[t] = nm;
    }
  }
  if (col == 0) {
#pragma unroll
    for (int t = 0; t < 8; ++t) {
#pragma unroll
      for (int r = 0; r < 4; ++r) {
        int row = t * 16 + kg * 4 + r;
        sstat[(wv * 128 + row) * 2 + 0] = rmax[t][r];
        sstat[(wv * 128 + row) * 2 + 1] = rsum[t][r];
      }
    }
  }
  __syncthreads();
  if (tid < 128) {
    float m = -3.0e38f, ssum = 0.f;
#pragma unroll
    for (int w2 = 0; w2 < 4; ++w2) {
      float pm = sstat[(w2 * 128 + tid) * 2 + 0];
      float ps = sstat[(w2 * 128 + tid) * 2 + 1];
      float nm2 = fmaxf(m, pm);
      ssum = ssum * __expf(m - nm2) + ps * __expf(pm - nm2);
      m = nm2;
    }
    pmax[(size_t)(r0 + tid) * 16 + ch] = m;
    psum[(size_t)(r0 + tid) * 16 + ch] = ssum;
  }
}

// ---------------- target logit in f32: dot(h2[t], emb[tok[t]]) ----------------
__global__ __launch_bounds__(256) void k_tlogit(const int* __restrict__ tok,
                                                const float* __restrict__ emb,
                                                const float* __restrict__ h2buf,
                                                float* __restrict__ tlog) {
  const int wv = threadIdx.x >> 6, lane = threadIdx.x & 63;
  const int wgid = blockIdx.x * 4 + wv;
  for (int t = wgid; t < TSEQ; t += 128) {
    const float* hp = h2buf + (size_t)(t + 1) * DEMB + lane * 8;
    const float* ep = emb + (size_t)tok[t] * DEMB + lane * 8;
    float4 h0 = *(const float4*)hp, h1v = *(const float4*)(hp + 4);
    float4 e0 = *(const float4*)ep, e1v = *(const float4*)(ep + 4);
    float d = h0.x * e0.x + h0.y * e0.y + h0.z * e0.z + h0.w * e0.w +
              h1v.x * e1v.x + h1v.y * e1v.y + h1v.z * e1v.z + h1v.w * e1v.w;
    for (int m = 1; m < 64; m <<= 1) d += __shfl_xor(d, m);
    if (lane == 0) tlog[t] = d;
  }
}

// ---------------- final: sum_t (tlogit - lse) ----------------
__global__ void k_final(const float* __restrict__ pmax, const float* __restrict__ psum,
                        const float* __restrict__ tlog, float* __restrict__ out) {
  __shared__ float red[4];
  float local = 0.f;
  for (int t = threadIdx.x; t < TSEQ; t += 256) {
    float m = -3.0e38f, s = 0.f;
#pragma unroll
    for (int c = 0; c < 16; ++c) {
      float pm = pmax[t * 16 + c], ps = psum[t * 16 + c];
      float nm = fmaxf(m, pm);
      s = s * __expf(m - nm) + ps * __expf(pm - nm);
      m = nm;
    }
    local += tlog[t] - (m + __logf(s));
  }
  for (int d = 1; d < 64; d <<= 1) local += __shfl_xor(local, d);
  if ((threadIdx.x & 63) == 0) red[threadIdx.x >> 6] = local;
  __syncthreads();
  if (threadIdx.x == 0) out[0] = red[0] + red[1] + red[2] + red[3];
}

// ---------------- host ----------------
extern "C" void kernel_launch(void* const* d_in, const int* in_sizes, int n_in,
                              void* d_out, int out_size, void* d_ws, size_t ws_size,
                              hipStream_t stream) {
  (void)in_sizes; (void)n_in; (void)out_size; (void)ws_size;
  const int*   tok = (const int*)d_in[0];
  const float* emb = (const float*)d_in[1];
  const float* W1  = (const float*)d_in[2];
  const float* U1  = (const float*)d_in[3];
  const float* b1  = (const float*)d_in[4];
  const float* W2  = (const float*)d_in[5];
  const float* U2  = (const float*)d_in[6];
  const float* b2  = (const float*)d_in[7];
  float* out = (float*)d_out;

  char* ws = (char*)d_ws;
  size_t off = 0;
  auto alloc = [&](size_t bytes) {
    char* p = ws + off;
    off = (off + bytes + 255) & ~(size_t)255;
    return p;
  };
  float* h2buf = (float*)alloc((size_t)(TSEQ + 1) * DEMB * 4);
  unsigned short* h2b = (unsigned short*)alloc((size_t)TSEQ * DEMB * 2);
  float* pmax = (float*)alloc((size_t)TSEQ * 16 * 4);
  float* psum = (float*)alloc((size_t)TSEQ * 16 * 4);
  float* tlog = (float*)alloc((size_t)TSEQ * 4);
  // big region: [h2v][h1v][xW1] during k_rnn; embB (32.77MB) overlays from
  // offset 0 afterwards. Safe because k_init re-poisons all h slots at the
  // start of every launch before k_rnn runs.
  size_t sz_h2v = (size_t)(TSEQ + 1) * DEMB * 4;   //  4,196,352
  size_t sz_h1v = (size_t)(TSEQ + 1) * DHID * 4;   //  8,392,704
  size_t sz_xw1 = (size_t)TSEQ * DHID * 4;         //  8,388,608
  size_t sz_embB = (size_t)NVOCAB * DEMB * 2;      // 32,768,000
  size_t big_sz = sz_h2v + sz_h1v + sz_xw1;
  if (sz_embB > big_sz) big_sz = sz_embB;
  char* big = alloc(big_sz);
  float* h2v = (float*)big;
  float* h1v = (float*)(big + sz_h2v);
  float* xW1 = (float*)(big + sz_h2v + sz_h1v);
  unsigned short* embB = (unsigned short*)big;

  k_init<<<dim3(512), dim3(256), 0, stream>>>((uint4*)h1v, (uint4*)h2v);
  k_xw1<<<dim3(512), dim3(256), 0, stream>>>(tok, emb, W1, b1, xW1);
  k_rnn<<<dim3(96), dim3(256), 0, stream>>>(xW1, U1, W2, U2, b2, h1v, h2v, h2buf);
  k_conv<<<dim3(2048), dim3(256), 0, stream>>>(emb, h2buf + DEMB, embB, h2b);
  k_logits<<<dim3(256), dim3(256), 135168, stream>>>(h2b, embB, pmax, psum);
  k_tlogit<<<dim3(32), dim3(256), 0, stream>>>(tok, emb, h2buf, tlog);
  k_final<<<dim3(1), dim3(256), 0, stream>>>(pmax, psum, tlog, out);
}